// Round 1
// baseline (553.018 us; speedup 1.0000x reference)
//
#include <hip/hip_runtime.h>
#include <math.h>

#define NN 8192
#define NE 131072
#define NG 64
#define FIN 64
#define FE 32

static __device__ __forceinline__ float relu(float v){ return v > 0.f ? v : 0.f; }

// ---------------- counting sorts (src and dst CSR) ----------------
__global__ void k_hist(const int* __restrict__ ei, int* scnt, int* dcnt){
  int e = blockIdx.x*256 + threadIdx.x;
  if (e < NE){ atomicAdd(&scnt[ei[e]],1); atomicAdd(&dcnt[ei[NE+e]],1); }
}

__global__ void k_scan(const int* __restrict__ scnt, const int* __restrict__ dcnt,
                       int* soff, int* scur, int* doff, int* dcur){
  const int* cnt = (blockIdx.x==0) ? scnt : dcnt;
  int* off = (blockIdx.x==0) ? soff : doff;
  int* cur = (blockIdx.x==0) ? scur : dcur;
  __shared__ int sums[1024];
  int t = threadIdx.x;
  int v[8]; int s = 0;
  #pragma unroll
  for (int j=0;j<8;++j){ v[j]=cnt[t*8+j]; s+=v[j]; }
  sums[t]=s; __syncthreads();
  for (int d=1; d<1024; d<<=1){
    int val = (t>=d) ? sums[t-d] : 0;
    __syncthreads();
    sums[t] += val;
    __syncthreads();
  }
  int run = sums[t]-s;   // exclusive prefix
  #pragma unroll
  for (int j=0;j<8;++j){ off[t*8+j]=run; cur[t*8+j]=run; run+=v[j]; }
  if (t==1023) off[NN]=run;
}

__global__ void k_scatter(const int* __restrict__ ei, int* scur, int* dcur,
                          int* sperm, int* dperm){
  int e = blockIdx.x*256 + threadIdx.x;
  if (e < NE){
    int s = ei[e], d = ei[NE+e];
    sperm[atomicAdd(&scur[s],1)] = e;
    dperm[atomicAdd(&dcur[d],1)] = e;
  }
}

// ---------------- EdgeMLP layers 1+2 fused: edge_attr -> h2 [E,64] ----------------
__global__ __launch_bounds__(256) void k_mlp12(const float* __restrict__ EA,
      const float* __restrict__ W1, const float* __restrict__ B1,
      const float* __restrict__ W2, const float* __restrict__ B2,
      float* __restrict__ H2out){
  __shared__ float W1s[FE*128];
  __shared__ float W2s[128*64];
  __shared__ float B1s[128];
  __shared__ float B2s[64];
  __shared__ float eas[4][4][FE];
  __shared__ float h1s[4][4][128];
  int tid = threadIdx.x;
  int wv = tid >> 6, lane = tid & 63;
  for (int i=tid;i<FE*128;i+=256) W1s[i]=W1[i];
  for (int i=tid;i<128*64;i+=256) W2s[i]=W2[i];
  if (tid<128) B1s[tid]=B1[tid];
  if (tid<64)  B2s[tid]=B2[tid];
  int e0 = (blockIdx.x*4 + wv)*4;
  for (int j=lane;j<4*FE;j+=64) eas[wv][j>>5][j&31] = EA[e0*FE + j];
  __syncthreads();

  float a0[4], a1[4];
  #pragma unroll
  for (int e=0;e<4;++e){ a0[e]=B1s[lane]; a1[e]=B1s[64+lane]; }
  for (int kg=0; kg<8; ++kg){
    float w00=W1s[(kg*4+0)*128+lane],  w01=W1s[(kg*4+0)*128+64+lane];
    float w10=W1s[(kg*4+1)*128+lane],  w11=W1s[(kg*4+1)*128+64+lane];
    float w20=W1s[(kg*4+2)*128+lane],  w21=W1s[(kg*4+2)*128+64+lane];
    float w30=W1s[(kg*4+3)*128+lane],  w31=W1s[(kg*4+3)*128+64+lane];
    #pragma unroll
    for (int e=0;e<4;++e){
      float4 xv = *(const float4*)&eas[wv][e][kg*4];
      a0[e] += xv.x*w00 + xv.y*w10 + xv.z*w20 + xv.w*w30;
      a1[e] += xv.x*w01 + xv.y*w11 + xv.z*w21 + xv.w*w31;
    }
  }
  #pragma unroll
  for (int e=0;e<4;++e){ h1s[wv][e][lane]=relu(a0[e]); h1s[wv][e][64+lane]=relu(a1[e]); }
  __syncthreads();

  float c[4];
  #pragma unroll
  for (int e=0;e<4;++e) c[e]=B2s[lane];
  for (int kg=0; kg<32; ++kg){
    float w0=W2s[(kg*4+0)*64+lane];
    float w1=W2s[(kg*4+1)*64+lane];
    float w2=W2s[(kg*4+2)*64+lane];
    float w3=W2s[(kg*4+3)*64+lane];
    #pragma unroll
    for (int e=0;e<4;++e){
      float4 hv = *(const float4*)&h1s[wv][e][kg*4];
      c[e] += hv.x*w0 + hv.y*w1 + hv.z*w2 + hv.w*w3;
    }
  }
  #pragma unroll
  for (int e=0;e<4;++e) H2out[(size_t)(e0+e)*64+lane] = relu(c[e]);
}

// ---------------- P[n,k,o] = sum_i x[n,i] * W3[k, i*64+o] ----------------
__global__ __launch_bounds__(256) void k_pgen(const float* __restrict__ X,
      const float* __restrict__ W3, float* __restrict__ P){
  __shared__ float xs[16][64];
  int tid = threadIdx.x;
  int kk = tid>>6, o = tid&63;
  int n0 = blockIdx.x*16;
  for (int i=tid;i<16*64;i+=256) xs[i>>6][i&63] = X[(size_t)n0*64+i];
  __syncthreads();
  for (int ko=0; ko<16; ++ko){
    int k = ko*4 + kk;
    const float* wr = W3 + (size_t)k*4096 + o;
    float acc[16];
    #pragma unroll
    for (int n=0;n<16;++n) acc[n]=0.f;
    for (int ig=0; ig<16; ++ig){
      float w0 = wr[(ig*4+0)*64];
      float w1 = wr[(ig*4+1)*64];
      float w2 = wr[(ig*4+2)*64];
      float w3v= wr[(ig*4+3)*64];
      #pragma unroll
      for (int n=0;n<16;++n){
        float4 xv = *(const float4*)&xs[n][ig*4];
        acc[n] += xv.x*w0 + xv.y*w1 + xv.z*w2 + xv.w*w3v;
      }
    }
    float* pr = P + (size_t)n0*4096 + k*64 + o;
    #pragma unroll
    for (int n=0;n<16;++n) pr[(size_t)n*4096] = acc[n];
  }
}

// ---------------- agg init = x @ root_w + conv1_b ; xb = x @ b3mat ----------------
__global__ __launch_bounds__(256) void k_root(const float* __restrict__ X,
      const float* __restrict__ RW, const float* __restrict__ CB,
      const float* __restrict__ B3, float* __restrict__ AGG, float* __restrict__ XB){
  int tid=threadIdx.x, wv=tid>>6, lane=tid&63;
  int n = blockIdx.x*4 + wv;
  __shared__ float xr[4][64];
  xr[wv][lane] = X[(size_t)n*64+lane];
  __syncthreads();
  float aA = CB[lane], aB = 0.f;
  for (int ig=0; ig<16; ++ig){
    float4 xv = *(const float4*)&xr[wv][ig*4];
    int i0 = ig*4;
    aA += xv.x*RW[(i0+0)*64+lane] + xv.y*RW[(i0+1)*64+lane]
        + xv.z*RW[(i0+2)*64+lane] + xv.w*RW[(i0+3)*64+lane];
    aB += xv.x*B3[(i0+0)*64+lane] + xv.y*B3[(i0+1)*64+lane]
        + xv.z*B3[(i0+2)*64+lane] + xv.w*B3[(i0+3)*64+lane];
  }
  AGG[(size_t)n*64+lane]=aA; XB[(size_t)n*64+lane]=aB;
}

// ---------------- msg[e] = h2[e] @ P[src] + xb[src]; scatter-add to agg[dst] ----------------
__global__ __launch_bounds__(64) void k_msg(const float* __restrict__ P,
      const float* __restrict__ H2v, const float* __restrict__ XB,
      const int* __restrict__ ei, const int* __restrict__ soff,
      const int* __restrict__ sperm, float* __restrict__ AGG){
  __shared__ float Pl[4096];
  __shared__ float h2r[64];
  int lane = threadIdx.x;
  int n = blockIdx.x;
  const float4* ps = (const float4*)(P + (size_t)n*4096);
  float4* pl = (float4*)Pl;
  for (int i=lane;i<1024;i+=64) pl[i]=ps[i];
  float xbv = XB[(size_t)n*64+lane];
  int beg = soff[n], end = soff[n+1];
  __syncthreads();
  for (int idx=beg; idx<end; ++idx){
    int e = sperm[idx];
    h2r[lane] = H2v[(size_t)e*64+lane];
    __syncthreads();
    float acc = xbv;
    for (int kg=0;kg<16;++kg){
      float4 hv = *(const float4*)&h2r[kg*4];
      acc += hv.x*Pl[(kg*4+0)*64+lane] + hv.y*Pl[(kg*4+1)*64+lane]
           + hv.z*Pl[(kg*4+2)*64+lane] + hv.w*Pl[(kg*4+3)*64+lane];
    }
    int d = ei[NE+e];
    atomicAdd(&AGG[(size_t)d*64+lane], acc);
    __syncthreads();
  }
}

// ---------------- hg = relu(agg) @ gat_w ; per-node attn scalars ----------------
__global__ __launch_bounds__(256) void k_hg(const float* __restrict__ AGG,
      const float* __restrict__ GW, const float* __restrict__ ASRC,
      const float* __restrict__ ADST, float* __restrict__ HG,
      float* __restrict__ AS, float* __restrict__ AD){
  int tid=threadIdx.x, wv=tid>>6, lane=tid&63;
  int n = blockIdx.x*4+wv;
  __shared__ float xr[4][64];
  xr[wv][lane] = relu(AGG[(size_t)n*64+lane]);
  __syncthreads();
  float acc=0.f;
  for (int ig=0; ig<16; ++ig){
    float4 xv = *(const float4*)&xr[wv][ig*4];
    int i0=ig*4;
    acc += xv.x*GW[(i0+0)*64+lane] + xv.y*GW[(i0+1)*64+lane]
         + xv.z*GW[(i0+2)*64+lane] + xv.w*GW[(i0+3)*64+lane];
  }
  HG[(size_t)n*64+lane]=acc;
  float t1 = acc*ASRC[lane], t2 = acc*ADST[lane];
  #pragma unroll
  for (int d=32; d>=1; d>>=1){ t1 += __shfl_xor(t1,d); t2 += __shfl_xor(t2,d); }
  if (lane==0){ AS[n]=t1; AD[n]=t2; }
}

// ---------------- GAT softmax + aggregate per dst node (incl self-loop) ----------------
__global__ __launch_bounds__(64) void k_gat(const float* __restrict__ HG,
      const float* __restrict__ AS, const float* __restrict__ AD,
      const float* __restrict__ GB, const int* __restrict__ ei,
      const int* __restrict__ doff, const int* __restrict__ dperm,
      float* __restrict__ X2){
  int lane = threadIdx.x;
  int n = blockIdx.x;
  int beg = doff[n], end = doff[n+1], deg = end-beg;
  float adn = AD[n];
  float selfsc = AS[n] + adn; selfsc = selfsc>0.f ? selfsc : 0.2f*selfsc;
  float lmax = -3.4e38f;
  for (int j=lane; j<deg; j+=64){
    int e = dperm[beg+j];
    float sc = AS[ei[e]] + adn; sc = sc>0.f ? sc : 0.2f*sc;
    lmax = fmaxf(lmax, sc);
  }
  #pragma unroll
  for (int d=32; d>=1; d>>=1) lmax = fmaxf(lmax, __shfl_xor(lmax,d));
  float mx = fmaxf(lmax, selfsc);
  float lsum = 0.f;
  for (int j=lane; j<deg; j+=64){
    int e = dperm[beg+j];
    float sc = AS[ei[e]] + adn; sc = sc>0.f ? sc : 0.2f*sc;
    lsum += expf(sc-mx);
  }
  #pragma unroll
  for (int d=32; d>=1; d>>=1) lsum += __shfl_xor(lsum,d);
  float wself = expf(selfsc-mx);
  float denom = lsum + wself;
  float acc = wself * HG[(size_t)n*64+lane];
  for (int idx=beg; idx<end; ++idx){
    int e = dperm[idx];
    int s = ei[e];
    float sc = AS[s] + adn; sc = sc>0.f ? sc : 0.2f*sc;
    float wgt = expf(sc-mx);
    acc += wgt * HG[(size_t)s*64+lane];
  }
  X2[(size_t)n*64+lane] = relu(acc/denom + GB[lane]);
}

// ---------------- mean-pool per graph + 3-layer MLP head ----------------
__global__ __launch_bounds__(64) void k_head(const float* __restrict__ X2,
      const int* __restrict__ batch,
      const float* __restrict__ F1W, const float* __restrict__ F1B,
      const float* __restrict__ F2W, const float* __restrict__ F2B,
      const float* __restrict__ F3W, const float* __restrict__ F3B,
      float* __restrict__ OUT){
  int lane = threadIdx.x;
  int g = blockIdx.x;
  int lo=0, hi=NN;
  while (lo<hi){ int m=(lo+hi)>>1; if (batch[m] < g) lo=m+1; else hi=m; }
  int start = lo;
  lo=0; hi=NN;
  while (lo<hi){ int m=(lo+hi)>>1; if (batch[m] < g+1) lo=m+1; else hi=m; }
  int stop = lo;
  float s = 0.f;
  for (int r=start; r<stop; ++r) s += X2[(size_t)r*64+lane];
  float cnt = (float)(stop-start);
  float mean = s / fmaxf(cnt, 1.f);
  __shared__ float ms[64];
  __shared__ float g1[128];
  __shared__ float g2[64];
  ms[lane]=mean;
  __syncthreads();
  float a0=F1B[lane], a1=F1B[64+lane];
  for (int ig=0; ig<16; ++ig){
    float4 mv = *(const float4*)&ms[ig*4];
    int i0=ig*4;
    a0 += mv.x*F1W[(i0+0)*128+lane] + mv.y*F1W[(i0+1)*128+lane]
        + mv.z*F1W[(i0+2)*128+lane] + mv.w*F1W[(i0+3)*128+lane];
    a1 += mv.x*F1W[(i0+0)*128+64+lane] + mv.y*F1W[(i0+1)*128+64+lane]
        + mv.z*F1W[(i0+2)*128+64+lane] + mv.w*F1W[(i0+3)*128+64+lane];
  }
  g1[lane]=relu(a0); g1[64+lane]=relu(a1);
  __syncthreads();
  float b = F2B[lane];
  for (int kg=0; kg<32; ++kg){
    float4 gv = *(const float4*)&g1[kg*4];
    int k0=kg*4;
    b += gv.x*F2W[(k0+0)*64+lane] + gv.y*F2W[(k0+1)*64+lane]
       + gv.z*F2W[(k0+2)*64+lane] + gv.w*F2W[(k0+3)*64+lane];
  }
  g2[lane]=relu(b);
  __syncthreads();
  if (lane < 32){
    float cc = F3B[lane];
    for (int kg=0; kg<16; ++kg){
      float4 gv = *(const float4*)&g2[kg*4];
      int k0=kg*4;
      cc += gv.x*F3W[(k0+0)*32+lane] + gv.y*F3W[(k0+1)*32+lane]
          + gv.z*F3W[(k0+2)*32+lane] + gv.w*F3W[(k0+3)*32+lane];
    }
    OUT[g*32+lane] = relu(cc);
  }
}

extern "C" void kernel_launch(void* const* d_in, const int* in_sizes, int n_in,
                              void* d_out, int out_size, void* d_ws, size_t ws_size,
                              hipStream_t stream){
  const float* X   = (const float*)d_in[0];
  const float* EA  = (const float*)d_in[1];
  const float* W1  = (const float*)d_in[2];
  const float* B1  = (const float*)d_in[3];
  const float* W2  = (const float*)d_in[4];
  const float* B2  = (const float*)d_in[5];
  const float* W3  = (const float*)d_in[6];
  const float* B3  = (const float*)d_in[7];
  const float* RW  = (const float*)d_in[8];
  const float* CB  = (const float*)d_in[9];
  const float* GW  = (const float*)d_in[10];
  const float* ASRC= (const float*)d_in[11];
  const float* ADST= (const float*)d_in[12];
  const float* GB  = (const float*)d_in[13];
  const float* F1W = (const float*)d_in[14];
  const float* F1B = (const float*)d_in[15];
  const float* F2W = (const float*)d_in[16];
  const float* F2B = (const float*)d_in[17];
  const float* F3W = (const float*)d_in[18];
  const float* F3B = (const float*)d_in[19];
  const int*   EI  = (const int*)d_in[20];
  const int*   BATCH = (const int*)d_in[21];
  float* OUT = (float*)d_out;
  (void)in_sizes; (void)n_in; (void)out_size; (void)ws_size;

  char* w = (char*)d_ws;
  size_t off = 0;
  auto alloc = [&](size_t bytes)->char*{
    char* p = w + off; off = (off + bytes + 255) & ~(size_t)255; return p;
  };
  float* P    = (float*)alloc((size_t)NN*4096*4);   // 134 MB
  float* H2v  = (float*)alloc((size_t)NE*64*4);     // 33.5 MB
  float* XB   = (float*)alloc((size_t)NN*64*4);
  float* AGG  = (float*)alloc((size_t)NN*64*4);
  float* HGv  = (float*)alloc((size_t)NN*64*4);
  float* X2   = (float*)alloc((size_t)NN*64*4);
  float* AS   = (float*)alloc((size_t)NN*4);
  float* AD   = (float*)alloc((size_t)NN*4);
  int* scnt = (int*)alloc((size_t)NN*4);
  int* dcnt = (int*)alloc((size_t)NN*4);
  int* soff = (int*)alloc((size_t)(NN+1)*4);
  int* doff = (int*)alloc((size_t)(NN+1)*4);
  int* scur = (int*)alloc((size_t)NN*4);
  int* dcur = (int*)alloc((size_t)NN*4);
  int* sperm= (int*)alloc((size_t)NE*4);
  int* dperm= (int*)alloc((size_t)NE*4);

  hipMemsetAsync(scnt, 0, NN*4, stream);
  hipMemsetAsync(dcnt, 0, NN*4, stream);
  k_hist<<<NE/256,256,0,stream>>>(EI, scnt, dcnt);
  k_scan<<<2,1024,0,stream>>>(scnt,dcnt,soff,scur,doff,dcur);
  k_scatter<<<NE/256,256,0,stream>>>(EI,scur,dcur,sperm,dperm);
  k_mlp12<<<NE/16,256,0,stream>>>(EA,W1,B1,W2,B2,H2v);
  k_pgen<<<NN/16,256,0,stream>>>(X,W3,P);
  k_root<<<NN/4,256,0,stream>>>(X,RW,CB,B3,AGG,XB);
  k_msg<<<NN,64,0,stream>>>(P,H2v,XB,EI,soff,sperm,AGG);
  k_hg<<<NN/4,256,0,stream>>>(AGG,GW,ASRC,ADST,HGv,AS,AD);
  k_gat<<<NN,64,0,stream>>>(HGv,AS,AD,GB,EI,doff,dperm,X2);
  k_head<<<NG,64,0,stream>>>(X2,BATCH,F1W,F1B,F2W,F2B,F3W,F3B,OUT);
}